// Round 1
// baseline (1220.058 us; speedup 1.0000x reference)
//
#include <hip/hip_runtime.h>

#define B_ 16
#define C_ 192
#define T_ 2048
#define F_ 256
#define HALF_ 96

__device__ __forceinline__ float gelu_f(float x) {
  return 0.5f * x * (1.f + erff(x * 0.70710678118654752f));
}

// ---------------------------------------------------------------------------
// K1: h[b,f,t] = pre_w[f,:] @ x0[b,:,t] + pre_b[f]
// grid (T/256, F/8, B), block 256 (one t per thread, 8 f per thread)
// ---------------------------------------------------------------------------
__global__ void pre_gemm_k(const float* __restrict__ x,
                           const float* __restrict__ pw,
                           const float* __restrict__ pb,
                           float* __restrict__ h) {
  int t = blockIdx.x * 256 + threadIdx.x;
  int f0 = blockIdx.y * 8;
  int b = blockIdx.z;
  float acc[8];
#pragma unroll
  for (int j = 0; j < 8; ++j) acc[j] = pb[f0 + j];
  const float* xp = x + ((size_t)b * C_) * T_ + t;   // x0 = x[:, :96]
  const float* wp = pw + (size_t)f0 * HALF_;
#pragma unroll 4
  for (int c = 0; c < HALF_; ++c) {
    float xv = xp[(size_t)c * T_];
#pragma unroll
    for (int j = 0; j < 8; ++j)
      acc[j] = fmaf(wp[j * HALF_ + c], xv, acc[j]);
  }
  float* hp = h + ((size_t)b * F_ + f0) * T_ + t;
#pragma unroll
  for (int j = 0; j < 8; ++j) hp[(size_t)j * T_] = acc[j];
}

// ---------------------------------------------------------------------------
// K2: one WaveNet-ish layer, fused:
//   y1 = gelu(cnorm(dwconv(h_in*mask)))        (LDS, per (b, 64-t) tile)
//   y2 = gelu(cnorm(pw_w @ y1 + pw_b))
//   h_out = h_in + y2
// block 256 = 32 o-groups x 8 t-groups for the GEMM; LDS y1[256][68]
// ---------------------------------------------------------------------------
__global__ __launch_bounds__(256, 2) void layer_k(
    const float* __restrict__ h_in, float* __restrict__ h_out,
    const float* __restrict__ mask,
    const float* __restrict__ dww, const float* __restrict__ dwb,
    const float* __restrict__ g1, const float* __restrict__ b1,
    const float* __restrict__ pww, const float* __restrict__ pwb,
    const float* __restrict__ g2, const float* __restrict__ b2,
    int dil) {
  __shared__ float y1[F_ * 68];    // [c][t], stride 68 -> bank (4c+t)%32
  __shared__ float redA[8 * 64];   // 4 groups x 64 t, sums then sumsq
  __shared__ float stat[2 * 64];   // mean, rstd
  int tid = threadIdx.x;
  int b = blockIdx.y;
  int t0 = blockIdx.x * 64;

  // ---- Phase A: depthwise conv (+bias) + partial channel stats ----
  {
    int t = tid & 63, cg = tid >> 6;
    int tz = t0 + t;
    int tm = tz - dil, tp = tz + dil;
    bool vm = (tm >= 0), vp = (tp < T_);
    float mm = vm ? mask[b * T_ + tm] : 0.f;
    float mz = mask[b * T_ + tz];
    float mp = vp ? mask[b * T_ + tp] : 0.f;
    const float* hb = h_in + ((size_t)b * F_) * T_;
    float s = 0.f, q = 0.f;
#pragma unroll 4
    for (int k = 0; k < 64; ++k) {
      int c = cg * 64 + k;
      const float* hr = hb + (size_t)c * T_;
      float v0 = vm ? hr[tm] * mm : 0.f;
      float v1 = hr[tz] * mz;
      float v2 = vp ? hr[tp] * mp : 0.f;
      float v = fmaf(dww[c * 3], v0,
                fmaf(dww[c * 3 + 1], v1,
                fmaf(dww[c * 3 + 2], v2, dwb[c])));
      y1[c * 68 + t] = v;
      s += v;
      q = fmaf(v, v, q);
    }
    redA[cg * 64 + t] = s;
    redA[256 + cg * 64 + t] = q;
  }
  __syncthreads();
  if (tid < 64) {
    float s = redA[tid] + redA[64 + tid] + redA[128 + tid] + redA[192 + tid];
    float q = redA[256 + tid] + redA[320 + tid] + redA[384 + tid] + redA[448 + tid];
    float mean = s * (1.f / 256.f);
    float var = q * (1.f / 256.f) - mean * mean;
    stat[tid] = mean;
    stat[64 + tid] = rsqrtf(var + 1e-5f);
  }
  __syncthreads();
  // ---- Phase A3: normalize + gelu in place ----
  {
    int t = tid & 63, cg = tid >> 6;
    float mean = stat[t], rstd = stat[64 + t];
#pragma unroll 4
    for (int k = 0; k < 64; ++k) {
      int c = cg * 64 + k;
      float v = y1[c * 68 + t];
      v = (v - mean) * rstd * g1[c] + b1[c];
      y1[c * 68 + t] = gelu_f(v);
    }
  }
  __syncthreads();
  // ---- Phase B: pointwise GEMM (256x256) @ y1[256][64], tile 8o x 8t ----
  int og = tid >> 3, tg = tid & 7;
  int o0 = og * 8, tb = tg * 8;
  float acc[8][8];
#pragma unroll
  for (int j = 0; j < 8; ++j) {
    float pv = pwb[o0 + j];
#pragma unroll
    for (int k = 0; k < 8; ++k) acc[j][k] = pv;
  }
#pragma unroll 1
  for (int c = 0; c < F_; c += 4) {
    float4 w4[8];
#pragma unroll
    for (int j = 0; j < 8; ++j)
      w4[j] = *(const float4*)(pww + (size_t)(o0 + j) * F_ + c);
#pragma unroll
    for (int cc = 0; cc < 4; ++cc) {
      float4 xlo = *(const float4*)&y1[(c + cc) * 68 + tb];
      float4 xhi = *(const float4*)&y1[(c + cc) * 68 + tb + 4];
#pragma unroll
      for (int j = 0; j < 8; ++j) {
        float w = cc == 0 ? w4[j].x : cc == 1 ? w4[j].y : cc == 2 ? w4[j].z : w4[j].w;
        acc[j][0] = fmaf(w, xlo.x, acc[j][0]);
        acc[j][1] = fmaf(w, xlo.y, acc[j][1]);
        acc[j][2] = fmaf(w, xlo.z, acc[j][2]);
        acc[j][3] = fmaf(w, xlo.w, acc[j][3]);
        acc[j][4] = fmaf(w, xhi.x, acc[j][4]);
        acc[j][5] = fmaf(w, xhi.y, acc[j][5]);
        acc[j][6] = fmaf(w, xhi.z, acc[j][6]);
        acc[j][7] = fmaf(w, xhi.w, acc[j][7]);
      }
    }
  }
  __syncthreads();  // all y1 reads done -> safe to overlay reduction scratch
  // ---- Phase C: channel stats of y2 (partials overlaid into y1 space) ----
  float* redC = y1;  // [32][65] sums, then [32][65] sumsq
#pragma unroll
  for (int k = 0; k < 8; ++k) {
    float s = 0.f, q = 0.f;
#pragma unroll
    for (int j = 0; j < 8; ++j) {
      float v = acc[j][k];
      s += v;
      q = fmaf(v, v, q);
    }
    redC[og * 65 + tb + k] = s;
    redC[32 * 65 + og * 65 + tb + k] = q;
  }
  __syncthreads();
  if (tid < 64) {
    float s = 0.f, q = 0.f;
#pragma unroll
    for (int g = 0; g < 32; ++g) {
      s += redC[g * 65 + tid];
      q += redC[32 * 65 + g * 65 + tid];
    }
    float mean = s * (1.f / 256.f);
    float var = q * (1.f / 256.f) - mean * mean;
    stat[tid] = mean;
    stat[64 + tid] = rsqrtf(var + 1e-5f);
  }
  __syncthreads();
  // ---- normalize + gelu + residual + store ----
  const float* hbr = h_in + ((size_t)b * F_) * T_ + t0;
  float* ho = h_out + ((size_t)b * F_) * T_ + t0;
#pragma unroll
  for (int j = 0; j < 8; ++j) {
    int o = o0 + j;
    float gg = g2[o], bb = b2[o];
    float4 r0 = *(const float4*)(hbr + (size_t)o * T_ + tb);
    float4 r1 = *(const float4*)(hbr + (size_t)o * T_ + tb + 4);
    float v[8];
#pragma unroll
    for (int k = 0; k < 8; ++k) {
      int t = tb + k;
      float u = (acc[j][k] - stat[t]) * stat[64 + t] * gg + bb;
      v[k] = gelu_f(u);
    }
    float4 w0 = make_float4(r0.x + v[0], r0.y + v[1], r0.z + v[2], r0.w + v[3]);
    float4 w1 = make_float4(r1.x + v[4], r1.y + v[5], r1.z + v[6], r1.w + v[7]);
    *(float4*)(ho + (size_t)o * T_ + tb) = w0;
    *(float4*)(ho + (size_t)o * T_ + tb + 4) = w1;
  }
}

// ---------------------------------------------------------------------------
// K3: fused proj GEMM (232-row channel-chunk) + RQ spline + logdet
// grid (T/64, 12, B); block 256. LDS holds h-tile then (overlay) the 232x64
// logits tile; spline consumes 29 logits per (channel, t) from LDS.
// ---------------------------------------------------------------------------
__global__ __launch_bounds__(256, 2) void proj_spline_k(
    const float* __restrict__ h, const float* __restrict__ x,
    const float* __restrict__ mask,
    const float* __restrict__ pw, const float* __restrict__ pb,
    float* __restrict__ out, float* __restrict__ logdet) {
  __shared__ float lds[F_ * 68];
  __shared__ float red[4];
  int tid = threadIdx.x;
  int t0 = blockIdx.x * 64;
  int chunk = blockIdx.y;  // 8 channels -> 232 proj rows
  int b = blockIdx.z;

  // ---- stage h-tile * mask ----
  {
    int tloc = (tid & 15) * 4;
    int crow = tid >> 4;
    float4 m4 = *(const float4*)(mask + (size_t)b * T_ + t0 + tloc);
#pragma unroll
    for (int r = 0; r < 256; r += 16) {
      int c = r + crow;
      float4 v = *(const float4*)(h + ((size_t)b * F_ + c) * T_ + t0 + tloc);
      v.x *= m4.x; v.y *= m4.y; v.z *= m4.z; v.w *= m4.w;
      *(float4*)&lds[c * 68 + tloc] = v;
    }
  }
  __syncthreads();
  // ---- GEMM: 232 rows x 64 t, thread tile 8o x 8t (232 active threads) ----
  int og = tid >> 3, tg = tid & 7;
  int tb = tg * 8;
  float acc[8][8];
#pragma unroll
  for (int j = 0; j < 8; ++j)
#pragma unroll
    for (int k = 0; k < 8; ++k) acc[j][k] = 0.f;
  if (og < 29) {
    const float* wbase = pw + ((size_t)chunk * 232 + og * 8) * F_;
#pragma unroll 1
    for (int c = 0; c < F_; c += 4) {
      float4 w4[8];
#pragma unroll
      for (int j = 0; j < 8; ++j)
        w4[j] = *(const float4*)(wbase + (size_t)j * F_ + c);
#pragma unroll
      for (int cc = 0; cc < 4; ++cc) {
        float4 xlo = *(const float4*)&lds[(c + cc) * 68 + tb];
        float4 xhi = *(const float4*)&lds[(c + cc) * 68 + tb + 4];
#pragma unroll
        for (int j = 0; j < 8; ++j) {
          float w = cc == 0 ? w4[j].x : cc == 1 ? w4[j].y : cc == 2 ? w4[j].z : w4[j].w;
          acc[j][0] = fmaf(w, xlo.x, acc[j][0]);
          acc[j][1] = fmaf(w, xlo.y, acc[j][1]);
          acc[j][2] = fmaf(w, xlo.z, acc[j][2]);
          acc[j][3] = fmaf(w, xlo.w, acc[j][3]);
          acc[j][4] = fmaf(w, xhi.x, acc[j][4]);
          acc[j][5] = fmaf(w, xhi.y, acc[j][5]);
          acc[j][6] = fmaf(w, xhi.z, acc[j][6]);
          acc[j][7] = fmaf(w, xhi.w, acc[j][7]);
        }
      }
    }
  }
  __syncthreads();  // all h-tile reads done -> overlay s-tile in same LDS
  if (og < 29) {
    float mv[8];
#pragma unroll
    for (int k = 0; k < 8; ++k) mv[k] = mask[(size_t)b * T_ + t0 + tb + k];
#pragma unroll
    for (int j = 0; j < 8; ++j) {
      float bias = pb[(size_t)chunk * 232 + og * 8 + j];
#pragma unroll
      for (int k = 0; k < 8; ++k)
        lds[(og * 8 + j) * 68 + tb + k] = (acc[j][k] + bias) * mv[k];
    }
  }
  __syncthreads();
  // ---- spline: 8 ch x 64 t per block; 2 elements per thread ----
  float lad_sum = 0.f;
  int ch_i = tid >> 5, ti = tid & 31;
  int ch = chunk * 8 + ch_i;
#pragma unroll 1
  for (int pass = 0; pass < 2; ++pass) {
    int t = ti + pass * 32;
    float s[29];
#pragma unroll
    for (int j = 0; j < 29; ++j) s[j] = lds[(ch_i * 29 + j) * 68 + t];
    float xin = x[((size_t)b * C_ + HALF_ + ch) * T_ + t0 + t];
    float mval = mask[(size_t)b * T_ + t0 + t];
    // widths -> cumwidths
    float uw[10];
    float mx = -1e30f;
#pragma unroll
    for (int j = 0; j < 10; ++j) { uw[j] = s[j] * 0.0625f; mx = fmaxf(mx, uw[j]); }
    float ew[10]; float esum = 0.f;
#pragma unroll
    for (int j = 0; j < 10; ++j) { ew[j] = expf(uw[j] - mx); esum += ew[j]; }
    float inv = 1.f / esum;
    float cw[11];
    cw[0] = -5.f;
    float csum = 0.f;
#pragma unroll
    for (int j = 0; j < 9; ++j) {
      csum += fmaf(0.99f, ew[j] * inv, 0.001f);
      cw[j + 1] = fmaf(10.f, csum, -5.f);
    }
    cw[10] = 5.f;
    // heights -> cumheights
    float uh[10]; mx = -1e30f;
#pragma unroll
    for (int j = 0; j < 10; ++j) { uh[j] = s[10 + j] * 0.0625f; mx = fmaxf(mx, uh[j]); }
    float eh[10]; esum = 0.f;
#pragma unroll
    for (int j = 0; j < 10; ++j) { eh[j] = expf(uh[j] - mx); esum += eh[j]; }
    inv = 1.f / esum;
    float chh[11];
    chh[0] = -5.f;
    csum = 0.f;
#pragma unroll
    for (int j = 0; j < 9; ++j) {
      csum += fmaf(0.99f, eh[j] * inv, 0.001f);
      chh[j + 1] = fmaf(10.f, csum, -5.f);
    }
    chh[10] = 5.f;
    // derivatives (edges = MIN_D + softplus(log(expm1(1-MIN_D))) = 1.0)
    float dv[11];
    dv[0] = 1.f; dv[10] = 1.f;
#pragma unroll
    for (int j = 1; j < 10; ++j) {
      float u = s[19 + j];
      float sp = (u > 15.f) ? u : log1pf(expf(u));
      dv[j] = 0.001f + sp;
    }
    float xc = fminf(fmaxf(xin, -5.f), 5.f);
    bool inside = (xin >= -5.f) && (xin <= 5.f);
    int idx = 0;
#pragma unroll
    for (int k = 1; k <= 10; ++k) idx += (xc >= cw[k]) ? 1 : 0;
    idx = idx > 9 ? 9 : idx;
    float in_cw = cw[0], in_w = cw[1] - cw[0];
    float in_ch = chh[0], in_h = chh[1] - chh[0];
    float d0 = dv[0], d1 = dv[1];
#pragma unroll
    for (int k = 1; k < 10; ++k) {
      bool sel = (idx == k);
      in_cw = sel ? cw[k] : in_cw;
      in_w = sel ? (cw[k + 1] - cw[k]) : in_w;
      in_ch = sel ? chh[k] : in_ch;
      in_h = sel ? (chh[k + 1] - chh[k]) : in_h;
      d0 = sel ? dv[k] : d0;
      d1 = sel ? dv[k + 1] : d1;
    }
    float theta = (xc - in_cw) / in_w;
    float delta = in_h / in_w;
    float omt = 1.f - theta;
    float t1m = theta * omt;
    float th2 = theta * theta;
    float denom = delta + (d0 + d1 - 2.f * delta) * t1m;
    float num = in_h * (delta * th2 + d0 * t1m);
    float outv = in_ch + num / denom;
    float dnum = delta * delta * (d1 * th2 + 2.f * delta * t1m + d0 * omt * omt);
    float lad = logf(dnum) - 2.f * logf(denom);
    float res = inside ? outv : xin;
    float ladv = inside ? lad : 0.f;
    out[((size_t)b * C_ + HALF_ + ch) * T_ + t0 + t] = res * mval;
    lad_sum += ladv * mval;
  }
  // block reduction of lad_sum, one atomic per block
#pragma unroll
  for (int off = 32; off > 0; off >>= 1)
    lad_sum += __shfl_down(lad_sum, off, 64);
  if ((tid & 63) == 0) red[tid >> 6] = lad_sum;
  __syncthreads();
  if (tid == 0)
    atomicAdd(logdet + b, red[0] + red[1] + red[2] + red[3]);
}

// ---------------------------------------------------------------------------
// K4: out[:, :96, :] = x0 * mask (vectorized passthrough)
// ---------------------------------------------------------------------------
__global__ void copy_x0_k(const float* __restrict__ x,
                          const float* __restrict__ mask,
                          float* __restrict__ out) {
  int i = blockIdx.x * 256 + threadIdx.x;  // 16 * 49152 float4's
  int b = i / (HALF_ * T_ / 4);
  int r = i - b * (HALF_ * T_ / 4);
  int t4 = r & (T_ / 4 - 1);
  float4 v = ((const float4*)(x + (size_t)b * C_ * T_))[r];
  float4 m = ((const float4*)(mask + (size_t)b * T_))[t4];
  v.x *= m.x; v.y *= m.y; v.z *= m.z; v.w *= m.w;
  ((float4*)(out + (size_t)b * C_ * T_))[r] = v;
}

extern "C" void kernel_launch(void* const* d_in, const int* in_sizes, int n_in,
                              void* d_out, int out_size, void* d_ws, size_t ws_size,
                              hipStream_t stream) {
  const float* x      = (const float*)d_in[0];
  const float* mask   = (const float*)d_in[1];
  const float* pre_w  = (const float*)d_in[2];
  const float* pre_b  = (const float*)d_in[3];
  const float* dw_w   = (const float*)d_in[4];
  const float* dw_b   = (const float*)d_in[5];
  const float* pw_w   = (const float*)d_in[6];
  const float* pw_b   = (const float*)d_in[7];
  const float* g1     = (const float*)d_in[8];
  const float* b1     = (const float*)d_in[9];
  const float* g2     = (const float*)d_in[10];
  const float* b2     = (const float*)d_in[11];
  const float* proj_w = (const float*)d_in[12];
  const float* proj_b = (const float*)d_in[13];
  float* out = (float*)d_out;
  float* logdet = out + (size_t)B_ * C_ * T_;
  float* hA = (float*)d_ws;                      // 16*256*2048 f32 = 32 MB
  float* hB = hA + (size_t)B_ * F_ * T_;         // second 32 MB

  hipMemsetAsync(logdet, 0, B_ * sizeof(float), stream);
  pre_gemm_k<<<dim3(T_ / 256, F_ / 8, B_), 256, 0, stream>>>(x, pre_w, pre_b, hA);
  layer_k<<<dim3(T_ / 64, B_), 256, 0, stream>>>(hA, hB, mask,
      dw_w, dw_b, g1, b1, pw_w, pw_b, g2, b2, 1);
  layer_k<<<dim3(T_ / 64, B_), 256, 0, stream>>>(hB, hA, mask,
      dw_w + F_ * 3, dw_b + F_, g1 + F_, b1 + F_,
      pw_w + F_ * F_, pw_b + F_, g2 + F_, b2 + F_, 3);
  layer_k<<<dim3(T_ / 64, B_), 256, 0, stream>>>(hA, hB, mask,
      dw_w + 2 * F_ * 3, dw_b + 2 * F_, g1 + 2 * F_, b1 + 2 * F_,
      pw_w + 2 * F_ * F_, pw_b + 2 * F_, g2 + 2 * F_, b2 + 2 * F_, 9);
  copy_x0_k<<<dim3(B_ * HALF_ * T_ / 4 / 256), 256, 0, stream>>>(x, mask, out);
  proj_spline_k<<<dim3(T_ / 64, 12, B_), 256, 0, stream>>>(hB, x, mask,
      proj_w, proj_b, out, logdet);
}